// Round 6
// baseline (873.106 us; speedup 1.0000x reference)
//
#include <hip/hip_runtime.h>

#define MM 4096
#define KK 4096
#define NN 11008
#define NP8 (NN/8)
#define KTILES (KK/32)
#define LDA 40
#define LDB 34
#define LDK 132   // pass-1b LDS transpose leading dim (shorts)

#define W_BYTES ((size_t)NN * KK * 2)          // 90,177,536
#define X_BYTES ((size_t)MM * KK * 2)          // 33,554,432
#define WS_NEED (W_BYTES + X_BYTES)

typedef __bf16 bf16x8 __attribute__((ext_vector_type(8)));
typedef float f32x4 __attribute__((ext_vector_type(4)));

__device__ __forceinline__ unsigned short b16(float a){
  union { __bf16 v; unsigned short u; } t;
  t.v = (__bf16)a;            // HW cvt, RNE
  return t.u;
}

// async global->LDS, 16B per lane; HW dest = wave-uniform base + lane*16
__device__ __forceinline__ void g2l16(const unsigned short* g, unsigned short* l){
  __builtin_amdgcn_global_load_lds(
      (const __attribute__((address_space(1))) unsigned int*)g,
      (__attribute__((address_space(3))) unsigned int*)l, 16, 0, 0);
}

// ---------------- pass 1a: x fp32 -> bf16 ----------------
__global__ __launch_bounds__(256) void cvt_x(const float* __restrict__ x,
                                             unsigned short* __restrict__ xb){
  size_t i = ((size_t)blockIdx.x * 256 + threadIdx.x) * 8;
  f32x4 a = *(const f32x4*)(x + i);
  f32x4 b = *(const f32x4*)(x + i + 4);
  union { unsigned short s[8]; uint4 u; } t;
  t.s[0]=b16(a[0]); t.s[1]=b16(a[1]); t.s[2]=b16(a[2]); t.s[3]=b16(a[3]);
  t.s[4]=b16(b[0]); t.s[5]=b16(b[1]); t.s[6]=b16(b[2]); t.s[7]=b16(b[3]);
  *(uint4*)(xb + i) = t.u;
}

// ---------------- pass 1b: AWQ dequant -> Wt[N][K] bf16 (LDS transpose) ----------------
__global__ __launch_bounds__(256) void dequant_w(
    const int* __restrict__ qweight, const int* __restrict__ qzeros,
    const float* __restrict__ scales, unsigned short* __restrict__ Wt){
  __shared__ unsigned short Ws[128 * LDK];
  const int t  = threadIdx.x;
  const int c0 = blockIdx.x * 16, n0 = blockIdx.x * 128;
  const int k0 = blockIdx.y * 128, g = blockIdx.y;   // group == 128 k-rows
  const int cl = t & 15;         // packed-col lane (coalesced)
  const int kl = t >> 4;         // 0..15
  const int c  = c0 + cl;

  float sreg[8], treg[8];
  {
    const float* sp = scales + (size_t)g*NN + 8*c;
    unsigned int qz = (unsigned int)qzeros[(size_t)g*NP8 + c];
    const int SH[8] = {0,16,4,20,8,24,12,28};
    #pragma unroll
    for (int j=0;j<8;j++){
      float s = sp[j];
      float z = (float)((qz >> SH[j]) & 0xFu);
      sreg[j] = s;
      treg[j] = -(128.0f + z) * s;
    }
  }

  #pragma unroll
  for (int it=0; it<8; ++it){
    const int kk = it*16 + kl;
    unsigned int q = (unsigned int)qweight[(size_t)(k0 + kk)*NP8 + c];
    const unsigned int M4v = 0x000F000Fu, BBv = 0x43004300u;
    unsigned int ea[4];
    ea[0] = ( q        & M4v) | BBv;
    ea[1] = ((q >> 4 ) & M4v) | BBv;
    ea[2] = ((q >> 8 ) & M4v) | BBv;
    ea[3] = ((q >> 12) & M4v) | BBv;
    #pragma unroll
    for (int j=0;j<8;j++){
      float e = (j&1) ? __uint_as_float(ea[j>>1] & 0xFFFF0000u)
                      : __uint_as_float(ea[j>>1] << 16);
      Ws[(8*cl + j)*LDK + kk] = b16(fmaf(e, sreg[j], treg[j]));
    }
  }
  __syncthreads();
  // write out coalesced along K
  #pragma unroll
  for (int it=0; it<16; ++it){
    const int n  = it*8 + (t >> 5);
    const int ko = 4 * (t & 31);
    uint2 v = *(const uint2*)(&Ws[n*LDK + ko]);
    *(uint2*)(&Wt[(size_t)(n0 + n)*KK + k0 + ko]) = v;
  }
}

// ---------------- pass 2: bf16 GEMM, m97 structure ----------------
__global__ __launch_bounds__(256) void gemm_bf16(
    const unsigned short* __restrict__ A,   // [M,K] bf16
    const unsigned short* __restrict__ B,   // [N,K] bf16
    const float* __restrict__ bias,
    float* __restrict__ out){
  __shared__ __align__(16) unsigned short As[128*32];  // 8KB, unpadded 64B rows
  __shared__ __align__(16) unsigned short Bs[128*32];

  const int tid  = threadIdx.x;
  const int wid  = tid >> 6;
  const int lane = tid & 63;
  const int l16  = lane & 15;
  const int quad = lane >> 4;
  const int wm   = (wid >> 1) * 64;
  const int wn   = (wid & 1) * 64;
  const int m0   = blockIdx.y * 128;
  const int n0   = blockIdx.x * 128;

  // staging: 256 lanes x 16B = 4KB/call -> rows 0..63; second call rows 64..127
  const int srow = tid >> 2, schk = tid & 3;
  const unsigned short* pa = A + (size_t)(m0 + srow)*KK + schk*8;
  const unsigned short* pb = B + (size_t)(n0 + srow)*KK + schk*8;
  unsigned short* la = As + tid*8;            // bytes: tid*16  (rows 0..63)
  unsigned short* lb = Bs + tid*8;
  const size_t half = (size_t)64*KK;          // +64 rows in global

  f32x4 acc[4][4];
  {
    float bv[4];
    #pragma unroll
    for (int ni=0;ni<4;ni++) bv[ni] = bias[n0 + wn + ni*16 + l16];
    #pragma unroll
    for (int mi=0;mi<4;mi++)
      #pragma unroll
      for (int ni=0;ni<4;ni++)
        acc[mi][ni] = (f32x4){bv[ni], bv[ni], bv[ni], bv[ni]};
  }

  #pragma unroll 1
  for (int kt = 0; kt < KTILES; ++kt) {
    __syncthreads();                 // prior tile's frag reads complete
    g2l16(pa,        la);            // A rows   0..63
    g2l16(pa + half, la + 2048);     // A rows  64..127 (LDS +4KB)
    g2l16(pb,        lb);            // B rows   0..63
    g2l16(pb + half, lb + 2048);     // B rows  64..127
    pa += 32; pb += 32;
    __syncthreads();                 // drains vmcnt(0): tiles resident

    bf16x8 af[4], bfr[4];
    #pragma unroll
    for (int mi=0;mi<4;mi++){
      union { uint4 u; bf16x8 v; } t;
      t.u = *(const uint4*)(&As[(wm + mi*16 + l16)*32 + quad*8]);
      af[mi] = t.v;
    }
    #pragma unroll
    for (int ni=0;ni<4;ni++){
      union { uint4 u; bf16x8 v; } t;
      t.u = *(const uint4*)(&Bs[(wn + ni*16 + l16)*32 + quad*8]);
      bfr[ni] = t.v;
    }
    #pragma unroll
    for (int mi=0;mi<4;mi++)
      #pragma unroll
      for (int ni=0;ni<4;ni++)
        acc[mi][ni] = __builtin_amdgcn_mfma_f32_16x16x32_bf16(af[mi], bfr[ni], acc[mi][ni], 0, 0, 0);
  }

  #pragma unroll
  for (int mi=0;mi<4;mi++)
    #pragma unroll
    for (int ni=0;ni<4;ni++){
      const int n = n0 + wn + ni*16 + l16;
      #pragma unroll
      for (int r=0;r<4;r++){
        const int m = m0 + wm + mi*16 + quad*4 + r;
        out[(size_t)m*NN + n] = acc[mi][ni][r];
      }
    }
}

// ---------------- fallback: round-4 fused kernel (passing, 705 us) ----------------
__global__ __launch_bounds__(256, 3) void awq_gemm_fused(
    const float* __restrict__ x, const int* __restrict__ qweight,
    const int* __restrict__ qzeros, const float* __restrict__ scales,
    const float* __restrict__ bias, float* __restrict__ out){
  __shared__ __align__(16) unsigned short As[128*LDA];
  __shared__ __align__(16) unsigned short Bs[128*LDB];
  const int tid  = threadIdx.x;
  const int wid  = tid >> 6;
  const int lane = tid & 63;
  const int l16  = lane & 15;
  const int quad = lane >> 4;
  const int wm   = (wid >> 1) * 64;
  const int wn   = (wid & 1) * 64;
  const int m0   = blockIdx.y * 128;
  const int n0   = blockIdx.x * 128;
  const int c0   = blockIdx.x * 16;
  const int ar = tid >> 3, kq = tid & 7;
  const float* pax = x + (size_t)(m0 + ar)*KK + kq*4;
  const int bc  = tid & 15;
  const int br0 = (tid >> 4) * 2;
  const int* pb = qweight + (size_t)br0*NP8 + c0 + bc;
  const int SH[8] = {0,16,4,20,8,24,12,28};
  float sreg[8], treg[8];
  f32x4 acc[4][4];
  {
    float bv[4];
    #pragma unroll
    for (int ni=0;ni<4;ni++) bv[ni] = bias[n0 + wn + ni*16 + l16];
    #pragma unroll
    for (int mi=0;mi<4;mi++)
      #pragma unroll
      for (int ni=0;ni<4;ni++)
        acc[mi][ni] = (f32x4){bv[ni], bv[ni], bv[ni], bv[ni]};
  }
  #pragma unroll 1
  for (int kt = 0; kt < KTILES; ++kt) {
    f32x4 av[4];
    #pragma unroll
    for (int i=0;i<4;i++) av[i] = *(const f32x4*)(pax + (size_t)i*32*KK);
    unsigned int q0 = (unsigned int)pb[0];
    unsigned int q1 = (unsigned int)pb[NP8];
    pax += 32; pb += (size_t)32*NP8;
    if ((kt & 3) == 0) {
      const int g = kt >> 2;
      const float* sp = scales + (size_t)g*NN + n0 + 8*bc;
      unsigned int qz = (unsigned int)qzeros[(size_t)g*NP8 + c0 + bc];
      #pragma unroll
      for (int j=0;j<8;j++){
        float s = sp[j];
        float z = (float)((qz >> SH[j]) & 0xFu);
        sreg[j] = s; treg[j] = -(128.0f + z) * s;
      }
    }
    __syncthreads();
    #pragma unroll
    for (int i=0;i<4;i++){
      union { unsigned short s[4]; uint2 u; } t;
      t.s[0]=b16(av[i][0]); t.s[1]=b16(av[i][1]);
      t.s[2]=b16(av[i][2]); t.s[3]=b16(av[i][3]);
      *(uint2*)(&As[(i*32 + ar)*LDA + kq*4]) = t.u;
    }
    {
      const unsigned int M4v = 0x000F000Fu, BBv = 0x43004300u;
      unsigned int ea[4], fa[4];
      ea[0]=(q0&M4v)|BBv; ea[1]=((q0>>4)&M4v)|BBv; ea[2]=((q0>>8)&M4v)|BBv; ea[3]=((q0>>12)&M4v)|BBv;
      fa[0]=(q1&M4v)|BBv; fa[1]=((q1>>4)&M4v)|BBv; fa[2]=((q1>>8)&M4v)|BBv; fa[3]=((q1>>12)&M4v)|BBv;
      #pragma unroll
      for (int j=0;j<8;j++){
        float e=(j&1)?__uint_as_float(ea[j>>1]&0xFFFF0000u):__uint_as_float(ea[j>>1]<<16);
        float f=(j&1)?__uint_as_float(fa[j>>1]&0xFFFF0000u):__uint_as_float(fa[j>>1]<<16);
        union { unsigned short s[2]; unsigned int u; } t;
        t.s[0]=b16(fmaf(e,sreg[j],treg[j])); t.s[1]=b16(fmaf(f,sreg[j],treg[j]));
        *(unsigned int*)(&Bs[(8*bc + j)*LDB + br0]) = t.u;
      }
    }
    __syncthreads();
    bf16x8 af[4], bfr[4];
    #pragma unroll
    for (int mi=0;mi<4;mi++){
      union { uint4 u; bf16x8 v; } t;
      t.u = *(const uint4*)(&As[(wm + mi*16 + l16)*LDA + quad*8]);
      af[mi] = t.v;
    }
    #pragma unroll
    for (int ni=0;ni<4;ni++){
      const unsigned int* bp = (const unsigned int*)(&Bs[(wn + ni*16 + l16)*LDB + quad*8]);
      union { unsigned int u[4]; bf16x8 v; } t;
      t.u[0]=bp[0]; t.u[1]=bp[1]; t.u[2]=bp[2]; t.u[3]=bp[3];
      bfr[ni] = t.v;
    }
    #pragma unroll
    for (int mi=0;mi<4;mi++)
      #pragma unroll
      for (int ni=0;ni<4;ni++)
        acc[mi][ni] = __builtin_amdgcn_mfma_f32_16x16x32_bf16(af[mi], bfr[ni], acc[mi][ni], 0, 0, 0);
  }
  #pragma unroll
  for (int mi=0;mi<4;mi++)
    #pragma unroll
    for (int ni=0;ni<4;ni++){
      const int n = n0 + wn + ni*16 + l16;
      #pragma unroll
      for (int r=0;r<4;r++){
        const int m = m0 + wm + mi*16 + quad*4 + r;
        out[(size_t)m*NN + n] = acc[mi][ni][r];
      }
    }
}

extern "C" void kernel_launch(void* const* d_in, const int* in_sizes, int n_in,
                              void* d_out, int out_size, void* d_ws, size_t ws_size,
                              hipStream_t stream) {
  const float* x  = (const float*)d_in[0];
  const int* qw   = (const int*)d_in[1];
  const int* qz   = (const int*)d_in[2];
  const float* sc = (const float*)d_in[3];
  const float* bi = (const float*)d_in[4];
  float* out = (float*)d_out;

  if (ws_size >= WS_NEED) {
    unsigned short* Wt = (unsigned short*)d_ws;                    // [N,K] bf16
    unsigned short* xb = (unsigned short*)((char*)d_ws + W_BYTES); // [M,K] bf16
    cvt_x<<<(MM*(size_t)KK)/8/256, 256, 0, stream>>>(x, xb);
    dequant_w<<<dim3(NP8/16, KK/128), 256, 0, stream>>>(qw, qz, sc, Wt);
    gemm_bf16<<<dim3(NN/128, MM/128), 256, 0, stream>>>(xb, Wt, bi, out);
  } else {
    awq_gemm_fused<<<dim3(NN/128, MM/128), 256, 0, stream>>>(x, qw, qz, sc, bi, out);
  }
}

// Round 7
// 739.619 us; speedup vs baseline: 1.1805x; 1.1805x over previous
//
#include <hip/hip_runtime.h>

#define MM 4096
#define KK 4096
#define NN 11008
#define NP8 (NN/8)
#define KTILES (KK/32)
#define LDA 40
#define LDB 34

#define W_BYTES ((size_t)NN * KK * 2)          // 90,177,536
#define X_BYTES ((size_t)MM * KK * 2)          // 33,554,432
#define WS_NEED (W_BYTES + X_BYTES)

typedef __bf16 bf16x8 __attribute__((ext_vector_type(8)));
typedef float f32x4 __attribute__((ext_vector_type(4)));

__device__ __forceinline__ unsigned short b16(float a){
  union { __bf16 v; unsigned short u; } t;
  t.v = (__bf16)a;            // HW cvt, RNE
  return t.u;
}

// async global->LDS, 16B per lane; HW dest = wave-uniform base + lane*16
__device__ __forceinline__ void g2l16(const unsigned short* g, unsigned short* l){
  __builtin_amdgcn_global_load_lds(
      (const __attribute__((address_space(1))) unsigned int*)g,
      (__attribute__((address_space(3))) unsigned int*)l, 16, 0, 0);
}

// ---------------- pass 1a: x fp32 -> bf16 ----------------
__global__ __launch_bounds__(256) void cvt_x(const float* __restrict__ x,
                                             unsigned short* __restrict__ xb){
  size_t i = ((size_t)blockIdx.x * 256 + threadIdx.x) * 8;
  f32x4 a = *(const f32x4*)(x + i);
  f32x4 b = *(const f32x4*)(x + i + 4);
  union { unsigned short s[8]; uint4 u; } t;
  t.s[0]=b16(a[0]); t.s[1]=b16(a[1]); t.s[2]=b16(a[2]); t.s[3]=b16(a[3]);
  t.s[4]=b16(b[0]); t.s[5]=b16(b[1]); t.s[6]=b16(b[2]); t.s[7]=b16(b[3]);
  *(uint4*)(xb + i) = t.u;
}

// ---------------- pass 1b: AWQ dequant -> Wt[N][K] bf16 ----------------
// Block: 128 n x 128 k (one group). 4 slabs of 32 k through a [128n][16 kp] u32
// LDS tile (stride 17 u32 -> 4-way write conflicts, free reads).
__global__ __launch_bounds__(256) void dequant_w(
    const int* __restrict__ qweight, const int* __restrict__ qzeros,
    const float* __restrict__ scales, unsigned short* __restrict__ Wt){
  __shared__ unsigned int Ws32[128 * 17];
  const int t  = threadIdx.x;
  const int c0 = blockIdx.x * 16, n0 = blockIdx.x * 128;
  const int k0 = blockIdx.y * 128, g = blockIdx.y;   // group == 128 k-rows
  const int bc = t & 15;          // packed col (coalesced)
  const int kp = t >> 4;          // 0..15 k-pairs within slab
  const int c  = c0 + bc;
  const int SH[8] = {0,16,4,20,8,24,12,28};          // 4*AWQ_ORDER[j]

  float sreg[8], treg[8];
  {
    const float* sp = scales + (size_t)g*NN + 8*c;
    unsigned int qz = (unsigned int)qzeros[(size_t)g*NP8 + c];
    #pragma unroll
    for (int j=0;j<8;j++){
      float s = sp[j];
      float z = (float)((qz >> SH[j]) & 0xFu);
      sreg[j] = s;
      treg[j] = -(128.0f + z) * s;
    }
  }

  const int prow = t >> 1;        // phase-2: row, half
  const int phalf = t & 1;

  #pragma unroll 1
  for (int s = 0; s < 4; ++s){
    const int kk = s*32 + 2*kp;
    unsigned int q0 = (unsigned int)qweight[(size_t)(k0 + kk    )*NP8 + c];
    unsigned int q1 = (unsigned int)qweight[(size_t)(k0 + kk + 1)*NP8 + c];
    const unsigned int M4v = 0x000F000Fu, BBv = 0x43004300u;
    unsigned int ea[4], fa[4];
    ea[0]=(q0&M4v)|BBv; ea[1]=((q0>>4)&M4v)|BBv; ea[2]=((q0>>8)&M4v)|BBv; ea[3]=((q0>>12)&M4v)|BBv;
    fa[0]=(q1&M4v)|BBv; fa[1]=((q1>>4)&M4v)|BBv; fa[2]=((q1>>8)&M4v)|BBv; fa[3]=((q1>>12)&M4v)|BBv;
    #pragma unroll
    for (int j=0;j<8;j++){
      float e=(j&1)?__uint_as_float(ea[j>>1]&0xFFFF0000u):__uint_as_float(ea[j>>1]<<16);
      float f=(j&1)?__uint_as_float(fa[j>>1]&0xFFFF0000u):__uint_as_float(fa[j>>1]<<16);
      float w0 = fmaf(e, sreg[j], treg[j]);    // k even
      float w1 = fmaf(f, sreg[j], treg[j]);    // k odd
      union { unsigned short h[2]; unsigned int u; } p;
      p.h[0]=b16(w0); p.h[1]=b16(w1);
      Ws32[(8*bc + j)*17 + kp] = p.u;
    }
    __syncthreads();
    // phase 2: write slab out; 2 threads cover one row's 64B (full lines)
    {
      unsigned int v[8];
      #pragma unroll
      for (int cidx=0;cidx<8;cidx++) v[cidx] = Ws32[prow*17 + phalf*8 + cidx];
      uint4 u0 = make_uint4(v[0],v[1],v[2],v[3]);
      uint4 u1 = make_uint4(v[4],v[5],v[6],v[7]);
      unsigned short* dst = Wt + (size_t)(n0 + prow)*KK + k0 + s*32 + phalf*16;
      *(uint4*)(dst)     = u0;
      *(uint4*)(dst + 8) = u1;
    }
    __syncthreads();
  }
}

// ---------------- pass 2: bf16 GEMM, m97 structure, m-fastest grid ----------------
__global__ __launch_bounds__(256) void gemm_bf16(
    const unsigned short* __restrict__ A,   // [M,K] bf16
    const unsigned short* __restrict__ B,   // [N,K] bf16
    const float* __restrict__ bias,
    float* __restrict__ out){
  __shared__ __align__(16) unsigned short As[128*32];  // 8KB, unpadded 64B rows
  __shared__ __align__(16) unsigned short Bs[128*32];

  const int tid  = threadIdx.x;
  const int wid  = tid >> 6;
  const int lane = tid & 63;
  const int l16  = lane & 15;
  const int quad = lane >> 4;
  const int wm   = (wid >> 1) * 64;
  const int wn   = (wid & 1) * 64;
  // m-fastest: gridDim.x = 32 m-tiles (32%8==0 -> XCD-pinned A working set),
  // consecutive blocks share the same B n-tile across all 8 XCDs.
  const int m0   = blockIdx.x * 128;
  const int n0   = blockIdx.y * 128;

  const int srow = tid >> 2, schk = tid & 3;
  const unsigned short* pa = A + (size_t)(m0 + srow)*KK + schk*8;
  const unsigned short* pb = B + (size_t)(n0 + srow)*KK + schk*8;
  unsigned short* la = As + tid*8;            // rows 0..63
  unsigned short* lb = Bs + tid*8;
  const size_t half = (size_t)64*KK;

  f32x4 acc[4][4];
  {
    float bv[4];
    #pragma unroll
    for (int ni=0;ni<4;ni++) bv[ni] = bias[n0 + wn + ni*16 + l16];
    #pragma unroll
    for (int mi=0;mi<4;mi++)
      #pragma unroll
      for (int ni=0;ni<4;ni++)
        acc[mi][ni] = (f32x4){bv[ni], bv[ni], bv[ni], bv[ni]};
  }

  #pragma unroll 1
  for (int kt = 0; kt < KTILES; ++kt) {
    __syncthreads();
    g2l16(pa,        la);            // A rows   0..63
    g2l16(pa + half, la + 2048);     // A rows  64..127
    g2l16(pb,        lb);            // B rows   0..63
    g2l16(pb + half, lb + 2048);     // B rows  64..127
    pa += 32; pb += 32;
    __syncthreads();

    bf16x8 af[4], bfr[4];
    #pragma unroll
    for (int mi=0;mi<4;mi++){
      union { uint4 u; bf16x8 v; } t;
      t.u = *(const uint4*)(&As[(wm + mi*16 + l16)*32 + quad*8]);
      af[mi] = t.v;
    }
    #pragma unroll
    for (int ni=0;ni<4;ni++){
      union { uint4 u; bf16x8 v; } t;
      t.u = *(const uint4*)(&Bs[(wn + ni*16 + l16)*32 + quad*8]);
      bfr[ni] = t.v;
    }
    #pragma unroll
    for (int mi=0;mi<4;mi++)
      #pragma unroll
      for (int ni=0;ni<4;ni++)
        acc[mi][ni] = __builtin_amdgcn_mfma_f32_16x16x32_bf16(af[mi], bfr[ni], acc[mi][ni], 0, 0, 0);
  }

  #pragma unroll
  for (int mi=0;mi<4;mi++)
    #pragma unroll
    for (int ni=0;ni<4;ni++){
      const int n = n0 + wn + ni*16 + l16;
      #pragma unroll
      for (int r=0;r<4;r++){
        const int m = m0 + wm + mi*16 + quad*4 + r;
        out[(size_t)m*NN + n] = acc[mi][ni][r];
      }
    }
}

// ---------------- fallback: round-4 fused kernel (passing, 705 us) ----------------
__global__ __launch_bounds__(256, 3) void awq_gemm_fused(
    const float* __restrict__ x, const int* __restrict__ qweight,
    const int* __restrict__ qzeros, const float* __restrict__ scales,
    const float* __restrict__ bias, float* __restrict__ out){
  __shared__ __align__(16) unsigned short As[128*LDA];
  __shared__ __align__(16) unsigned short Bs[128*LDB];
  const int tid  = threadIdx.x;
  const int wid  = tid >> 6;
  const int lane = tid & 63;
  const int l16  = lane & 15;
  const int quad = lane >> 4;
  const int wm   = (wid >> 1) * 64;
  const int wn   = (wid & 1) * 64;
  const int m0   = blockIdx.y * 128;
  const int n0   = blockIdx.x * 128;
  const int c0   = blockIdx.x * 16;
  const int ar = tid >> 3, kq = tid & 7;
  const float* pax = x + (size_t)(m0 + ar)*KK + kq*4;
  const int bc  = tid & 15;
  const int br0 = (tid >> 4) * 2;
  const int* pb = qweight + (size_t)br0*NP8 + c0 + bc;
  const int SH[8] = {0,16,4,20,8,24,12,28};
  float sreg[8], treg[8];
  f32x4 acc[4][4];
  {
    float bv[4];
    #pragma unroll
    for (int ni=0;ni<4;ni++) bv[ni] = bias[n0 + wn + ni*16 + l16];
    #pragma unroll
    for (int mi=0;mi<4;mi++)
      #pragma unroll
      for (int ni=0;ni<4;ni++)
        acc[mi][ni] = (f32x4){bv[ni], bv[ni], bv[ni], bv[ni]};
  }
  #pragma unroll 1
  for (int kt = 0; kt < KTILES; ++kt) {
    f32x4 av[4];
    #pragma unroll
    for (int i=0;i<4;i++) av[i] = *(const f32x4*)(pax + (size_t)i*32*KK);
    unsigned int q0 = (unsigned int)pb[0];
    unsigned int q1 = (unsigned int)pb[NP8];
    pax += 32; pb += (size_t)32*NP8;
    if ((kt & 3) == 0) {
      const int g = kt >> 2;
      const float* sp = scales + (size_t)g*NN + n0 + 8*bc;
      unsigned int qz = (unsigned int)qzeros[(size_t)g*NP8 + c0 + bc];
      #pragma unroll
      for (int j=0;j<8;j++){
        float s = sp[j];
        float z = (float)((qz >> SH[j]) & 0xFu);
        sreg[j] = s; treg[j] = -(128.0f + z) * s;
      }
    }
    __syncthreads();
    #pragma unroll
    for (int i=0;i<4;i++){
      union { unsigned short s[4]; uint2 u; } t;
      t.s[0]=b16(av[i][0]); t.s[1]=b16(av[i][1]);
      t.s[2]=b16(av[i][2]); t.s[3]=b16(av[i][3]);
      *(uint2*)(&As[(i*32 + ar)*LDA + kq*4]) = t.u;
    }
    {
      const unsigned int M4v = 0x000F000Fu, BBv = 0x43004300u;
      unsigned int ea[4], fa[4];
      ea[0]=(q0&M4v)|BBv; ea[1]=((q0>>4)&M4v)|BBv; ea[2]=((q0>>8)&M4v)|BBv; ea[3]=((q0>>12)&M4v)|BBv;
      fa[0]=(q1&M4v)|BBv; fa[1]=((q1>>4)&M4v)|BBv; fa[2]=((q1>>8)&M4v)|BBv; fa[3]=((q1>>12)&M4v)|BBv;
      #pragma unroll
      for (int j=0;j<8;j++){
        float e=(j&1)?__uint_as_float(ea[j>>1]&0xFFFF0000u):__uint_as_float(ea[j>>1]<<16);
        float f=(j&1)?__uint_as_float(fa[j>>1]&0xFFFF0000u):__uint_as_float(fa[j>>1]<<16);
        union { unsigned short s[2]; unsigned int u; } t;
        t.s[0]=b16(fmaf(e,sreg[j],treg[j])); t.s[1]=b16(fmaf(f,sreg[j],treg[j]));
        *(unsigned int*)(&Bs[(8*bc + j)*LDB + br0]) = t.u;
      }
    }
    __syncthreads();
    bf16x8 af[4], bfr[4];
    #pragma unroll
    for (int mi=0;mi<4;mi++){
      union { uint4 u; bf16x8 v; } t;
      t.u = *(const uint4*)(&As[(wm + mi*16 + l16)*LDA + quad*8]);
      af[mi] = t.v;
    }
    #pragma unroll
    for (int ni=0;ni<4;ni++){
      const unsigned int* bp = (const unsigned int*)(&Bs[(wn + ni*16 + l16)*LDB + quad*8]);
      union { unsigned int u[4]; bf16x8 v; } t;
      t.u[0]=bp[0]; t.u[1]=bp[1]; t.u[2]=bp[2]; t.u[3]=bp[3];
      bfr[ni] = t.v;
    }
    #pragma unroll
    for (int mi=0;mi<4;mi++)
      #pragma unroll
      for (int ni=0;ni<4;ni++)
        acc[mi][ni] = __builtin_amdgcn_mfma_f32_16x16x32_bf16(af[mi], bfr[ni], acc[mi][ni], 0, 0, 0);
  }
  #pragma unroll
  for (int mi=0;mi<4;mi++)
    #pragma unroll
    for (int ni=0;ni<4;ni++){
      const int n = n0 + wn + ni*16 + l16;
      #pragma unroll
      for (int r=0;r<4;r++){
        const int m = m0 + wm + mi*16 + quad*4 + r;
        out[(size_t)m*NN + n] = acc[mi][ni][r];
      }
    }
}

extern "C" void kernel_launch(void* const* d_in, const int* in_sizes, int n_in,
                              void* d_out, int out_size, void* d_ws, size_t ws_size,
                              hipStream_t stream) {
  const float* x  = (const float*)d_in[0];
  const int* qw   = (const int*)d_in[1];
  const int* qz   = (const int*)d_in[2];
  const float* sc = (const float*)d_in[3];
  const float* bi = (const float*)d_in[4];
  float* out = (float*)d_out;

  if (ws_size >= WS_NEED) {
    unsigned short* Wt = (unsigned short*)d_ws;                    // [N,K] bf16
    unsigned short* xb = (unsigned short*)((char*)d_ws + W_BYTES); // [M,K] bf16
    cvt_x<<<(MM*(size_t)KK)/8/256, 256, 0, stream>>>(x, xb);
    dequant_w<<<dim3(NP8/16, KK/128), 256, 0, stream>>>(qw, qz, sc, Wt);
    gemm_bf16<<<dim3(MM/128, NN/128), 256, 0, stream>>>(xb, Wt, bi, out);  // m-fastest
  } else {
    awq_gemm_fused<<<dim3(NN/128, MM/128), 256, 0, stream>>>(x, qw, qz, sc, bi, out);
  }
}